// Round 1
// baseline (338.600 us; speedup 1.0000x reference)
//
#include <hip/hip_runtime.h>
#include <hip/hip_bf16.h>

// GAT on fully-connected graph, N=4096, F=D=64, H=4, OUT=2.
// Key algebraic trick: e[t,s,h]=lrelu(dst_t+src_s); exp(lrelu) factors per branch:
//   src > -dst : weight = e^{dst} * e^{src}
//   src <= -dst: weight = e^{0.2 dst} * e^{0.2 src}
// Sort sources per head once; build suffix sums (pos branch) and prefix sums
// (neg branch) of weight*h2 over sorted order; each target = rank(-dst) +
// two 65-float row gathers. O(N^2 H D) -> O(N (D+logN) H).

#define N 4096
#define D 64
#define H 4
#define HD 256
#define TS 66           // row stride of SA/PB tables (65 cols: 64 dims + weight)

// ---------------- encoder: h0 = relu(x @ W_enc + b_enc) ----------------
__global__ __launch_bounds__(256) void k_encoder(const float* __restrict__ x,
                                                 const float* __restrict__ W,
                                                 const float* __restrict__ b,
                                                 float* __restrict__ h0) {
    __shared__ float Ws[64 * 64];
    __shared__ float xs[4][64];
    int tid = threadIdx.x;
    for (int i = tid; i < 1024; i += 256) ((float4*)Ws)[i] = ((const float4*)W)[i];
    int lr = tid >> 6, lane = tid & 63;
    int row = blockIdx.x * 4 + lr;
    xs[lr][lane] = x[row * 64 + lane];
    __syncthreads();
    float acc = b[lane];
#pragma unroll
    for (int k = 0; k < 64; ++k) acc = fmaf(xs[lr][k], Ws[k * 64 + lane], acc);
    h0[row * 64 + lane] = fmaxf(acc, 0.f);
}

// ---------------- proj: h2 = hin @ W ; ssrc/sdst = einsum(h2, a) ----------------
// col mapping: each lane owns 4 consecutive cols c = lane*4+cc  (float4 LDS reads)
// head of col c = c>>6 -> lanes h*16..h*16+15 per head; 16-lane shfl reduce.
__global__ __launch_bounds__(256) void k_proj(const float* __restrict__ hin,
                                              const float* __restrict__ W,
                                              const float* __restrict__ asrc,
                                              const float* __restrict__ adst,
                                              float* __restrict__ h2,
                                              float* __restrict__ ssrc,   // [H][N]
                                              float* __restrict__ sdst) { // [H][N]
    __shared__ float Ws[64 * 256];  // 64 KB
    int tid = threadIdx.x;
    for (int i = tid; i < 4096; i += 256) ((float4*)Ws)[i] = ((const float4*)W)[i];
    int lane = tid & 63, w = tid >> 6;
    float4 av = ((const float4*)asrc)[lane];
    float4 bv = ((const float4*)adst)[lane];
    __syncthreads();
    int r0 = blockIdx.x * 16;
    for (int rr = 0; rr < 4; ++rr) {
        int row = r0 + w * 4 + rr;
        float hval = hin[row * 64 + lane];
        float a0 = 0.f, a1 = 0.f, a2 = 0.f, a3 = 0.f;
#pragma unroll
        for (int k = 0; k < 64; ++k) {
            float hk = __shfl(hval, k);
            float4 wv = ((const float4*)(Ws + k * 256))[lane];
            a0 = fmaf(hk, wv.x, a0);
            a1 = fmaf(hk, wv.y, a1);
            a2 = fmaf(hk, wv.z, a2);
            a3 = fmaf(hk, wv.w, a3);
        }
        ((float4*)(h2 + row * 256))[lane] = make_float4(a0, a1, a2, a3);
        float ps = a0 * av.x + a1 * av.y + a2 * av.z + a3 * av.w;
        float pd = a0 * bv.x + a1 * bv.y + a2 * bv.z + a3 * bv.w;
#pragma unroll
        for (int off = 8; off > 0; off >>= 1) {
            ps += __shfl_down(ps, off);
            pd += __shfl_down(pd, off);
        }
        if ((lane & 15) == 0) {
            int h = lane >> 4;
            ssrc[h * N + row] = ps;
            sdst[h * N + row] = pd;
        }
    }
}

// ---------------- rank-sort per head (exact, deterministic) ----------------
// rank_i = #{j : v_j < v_i || (v_j == v_i && j < i)}  -> unique ranks.
__global__ __launch_bounds__(256) void k_rank(const float* __restrict__ ssrc, // [H][N]
                                              float* __restrict__ srtv,       // [H][N]
                                              int* __restrict__ srti) {       // [H][N]
    __shared__ __align__(16) float vs[N];
    int h = blockIdx.x >> 4, bi = blockIdx.x & 15;
    int tid = threadIdx.x;
    for (int i = tid; i < N; i += 256) vs[i] = ssrc[h * N + i];
    __syncthreads();
    int i = bi * 256 + tid;
    float vi = vs[i];
    const float4* vs4 = (const float4*)vs;
    int rank = 0;
#pragma unroll 8
    for (int j4 = 0; j4 < N / 4; ++j4) {
        float4 q = vs4[j4];
        int jb = j4 << 2;
        rank += (q.x < vi || (q.x == vi && jb < i));
        rank += (q.y < vi || (q.y == vi && jb + 1 < i));
        rank += (q.z < vi || (q.z == vi && jb + 2 < i));
        rank += (q.w < vi || (q.w == vi && jb + 3 < i));
    }
    srtv[h * N + rank] = vi;
    srti[h * N + rank] = i;
}

// ---------------- S1: per-chunk totals + weight arrays ----------------
// grid H*64, block 128 (cols 0..64 active; col 64 = weight column).
__global__ __launch_bounds__(128) void k_s1(const float* __restrict__ h2,
                                            const int* __restrict__ srti,
                                            const float* __restrict__ srtv,
                                            float* __restrict__ wA, float* __restrict__ wB,
                                            float* __restrict__ TA, float* __restrict__ TB) {
    int h = blockIdx.x >> 6, c = blockIdx.x & 63, col = threadIdx.x;
    __shared__ int pj[64];
    __shared__ float wa[64], wb[64];
    int j0 = c * 64;
    float m1 = srtv[h * N + N - 1];
    if (col < 64) {
        int j = j0 + col;
        pj[col] = srti[h * N + j];
        float sv = srtv[h * N + j];
        float a = expf(sv - m1);
        float b = expf(0.2f * (sv - m1));
        wa[col] = a; wb[col] = b;
        wA[h * N + j] = a; wB[h * N + j] = b;
    }
    __syncthreads();
    if (col >= 65) return;
    float accA = 0.f, accB = 0.f;
#pragma unroll 8
    for (int j = 0; j < 64; ++j) {
        float val = (col < 64) ? h2[pj[j] * HD + h * 64 + col] : 1.0f;
        accA = fmaf(wa[j], val, accA);
        accB = fmaf(wb[j], val, accB);
    }
    TA[(h * 64 + c) * TS + col] = accA;
    TB[(h * 64 + c) * TS + col] = accB;
}

// ---------------- S2: scan chunk totals -> offsets; boundary table rows ----------------
__global__ __launch_bounds__(128) void k_s2(const float* __restrict__ TA,
                                            const float* __restrict__ TB,
                                            float* __restrict__ OffA, float* __restrict__ OffB,
                                            float* __restrict__ SA, float* __restrict__ PB) {
    int h = blockIdx.x, col = threadIdx.x;
    if (col >= 65) return;
    float acc = 0.f;
#pragma unroll 8
    for (int c = 63; c >= 0; --c) {  // suffix offsets for A
        OffA[(h * 64 + c) * TS + col] = acc;
        acc += TA[(h * 64 + c) * TS + col];
    }
    acc = 0.f;
#pragma unroll 8
    for (int c = 0; c < 64; ++c) {   // prefix offsets for B
        OffB[(h * 64 + c) * TS + col] = acc;
        acc += TB[(h * 64 + c) * TS + col];
    }
    SA[(size_t)(h * (N + 1) + N) * TS + col] = 0.f;  // SA[N] = 0
    PB[(size_t)(h * (N + 1) + 0) * TS + col] = 0.f;  // PB[0] = 0
}

// ---------------- S3: full suffix/prefix tables ----------------
__global__ __launch_bounds__(128) void k_s3(const float* __restrict__ h2,
                                            const int* __restrict__ srti,
                                            const float* __restrict__ wA, const float* __restrict__ wB,
                                            const float* __restrict__ OffA, const float* __restrict__ OffB,
                                            float* __restrict__ SA, float* __restrict__ PB) {
    int h = blockIdx.x >> 6, c = blockIdx.x & 63, col = threadIdx.x;
    __shared__ int pj[64];
    __shared__ float wa[64], wb[64];
    int j0 = c * 64;
    if (col < 64) {
        pj[col] = srti[h * N + j0 + col];
        wa[col] = wA[h * N + j0 + col];
        wb[col] = wB[h * N + j0 + col];
    }
    __syncthreads();
    if (col >= 65) return;
    float v[64];
#pragma unroll
    for (int j = 0; j < 64; ++j)
        v[j] = (col < 64) ? h2[pj[j] * HD + h * 64 + col] : 1.0f;
    float acc = OffA[(h * 64 + c) * TS + col];
#pragma unroll
    for (int j = 63; j >= 0; --j) {  // SA[i] = sum_{j>=i} wA_j * v_j
        acc = fmaf(wa[j], v[j], acc);
        SA[(size_t)(h * (N + 1) + j0 + j) * TS + col] = acc;
    }
    acc = OffB[(h * 64 + c) * TS + col];
#pragma unroll
    for (int j = 0; j < 64; ++j) {   // PB[i] = sum_{j<i} wB_j * v_j
        acc = fmaf(wb[j], v[j], acc);
        PB[(size_t)(h * (N + 1) + j0 + j + 1) * TS + col] = acc;
    }
}

// ---------------- target: blend tables per (t,h), mean heads, +bias, relu ----------------
__global__ __launch_bounds__(256) void k_target(const float* __restrict__ sdst, // [H][N]
                                                const float* __restrict__ srtv, // [H][N]
                                                const float* __restrict__ SA,
                                                const float* __restrict__ PB,
                                                const float* __restrict__ bias,
                                                float* __restrict__ hout) {
    int t = blockIdx.x * 4 + (threadIdx.x >> 6);
    int lane = threadIdx.x & 63;
    float acc = 0.f;
#pragma unroll
    for (int h = 0; h < H; ++h) {
        const float* sv = srtv + h * N;
        float dst = sdst[h * N + t];
        float thr = -dst;
        float m1 = sv[N - 1];
        // two-level ballot search: k = #{j : sv[j] <= thr}
        unsigned long long b1 = __ballot(sv[lane * 64] <= thr);
        int c1 = __popcll(b1);
        int seg = c1 > 0 ? c1 - 1 : 0;
        unsigned long long b2 = __ballot(sv[seg * 64 + lane] <= thr);
        int k = seg * 64 + __popcll(b2);
        float u = dst + m1;
        float g = fmaxf(u, 0.2f * u);          // keeps both exps <= 1
        float wAt = expf(u - g);
        float wBt = expf(0.2f * u - g);
        const float* sa = SA + (size_t)(h * (N + 1) + k) * TS;
        const float* pb = PB + (size_t)(h * (N + 1) + k) * TS;
        float num = wAt * sa[lane] + wBt * pb[lane];
        float den = wAt * sa[64] + wBt * pb[64];
        acc += num / den;
    }
    acc = acc * 0.25f + bias[lane];
    hout[t * 64 + lane] = fmaxf(acc, 0.f);
}

// ---------------- heads: logits (clip, abs col1) + values ----------------
__global__ __launch_bounds__(256) void k_heads(const float* __restrict__ h,
                                               const float* __restrict__ Wact,
                                               const float* __restrict__ bact,
                                               const float* __restrict__ Wcri,
                                               const float* __restrict__ bcri,
                                               float* __restrict__ out) {
    int t = blockIdx.x * 4 + (threadIdx.x >> 6);
    int lane = threadIdx.x & 63;
    float hv = h[t * 64 + lane];
    float p0 = hv * Wact[lane * 2 + 0];
    float p1 = hv * Wact[lane * 2 + 1];
    float p2 = hv * Wcri[lane];
#pragma unroll
    for (int off = 32; off > 0; off >>= 1) {
        p0 += __shfl_down(p0, off);
        p1 += __shfl_down(p1, off);
        p2 += __shfl_down(p2, off);
    }
    if (lane == 0) {
        float l0 = fminf(fmaxf(p0 + bact[0], -5.f), 5.f);
        float l1 = fminf(fmaxf(p1 + bact[1], -5.f), 5.f);
        out[t * 2 + 0] = l0;
        out[t * 2 + 1] = fabsf(l1);
        out[2 * N + t] = p2 + bcri[0];
    }
}

extern "C" void kernel_launch(void* const* d_in, const int* in_sizes, int n_in,
                              void* d_out, int out_size, void* d_ws, size_t ws_size,
                              hipStream_t stream) {
    (void)in_sizes; (void)n_in; (void)out_size; (void)ws_size;
    const float* x     = (const float*)d_in[0];
    const float* W_enc = (const float*)d_in[1];
    const float* b_enc = (const float*)d_in[2];
    const float* W1    = (const float*)d_in[3];
    const float* as1   = (const float*)d_in[4];
    const float* ad1   = (const float*)d_in[5];
    const float* b1    = (const float*)d_in[6];
    const float* W2    = (const float*)d_in[7];
    const float* as2   = (const float*)d_in[8];
    const float* ad2   = (const float*)d_in[9];
    const float* b2    = (const float*)d_in[10];
    const float* W_act = (const float*)d_in[11];
    const float* b_act = (const float*)d_in[12];
    const float* W_cri = (const float*)d_in[13];
    const float* b_cri = (const float*)d_in[14];
    float* out = (float*)d_out;

    float* p = (float*)d_ws;
    float* h0   = p; p += N * D;
    float* hA   = p; p += N * D;
    float* hB   = p; p += N * D;
    float* h2   = p; p += N * HD;
    float* ssrc = p; p += H * N;
    float* sdst = p; p += H * N;
    float* srtv = p; p += H * N;
    int*   srti = (int*)p; p += H * N;
    float* wA   = p; p += H * N;
    float* wB   = p; p += H * N;
    float* TA   = p; p += H * 64 * TS;
    float* TB   = p; p += H * 64 * TS;
    float* OffA = p; p += H * 64 * TS;
    float* OffB = p; p += H * 64 * TS;
    float* SA   = p; p += (size_t)H * (N + 1) * TS;
    float* PB   = p; p += (size_t)H * (N + 1) * TS;

    k_encoder<<<N / 4, 256, 0, stream>>>(x, W_enc, b_enc, h0);

    // layer 1
    k_proj<<<N / 16, 256, 0, stream>>>(h0, W1, as1, ad1, h2, ssrc, sdst);
    k_rank<<<H * 16, 256, 0, stream>>>(ssrc, srtv, srti);
    k_s1<<<H * 64, 128, 0, stream>>>(h2, srti, srtv, wA, wB, TA, TB);
    k_s2<<<H, 128, 0, stream>>>(TA, TB, OffA, OffB, SA, PB);
    k_s3<<<H * 64, 128, 0, stream>>>(h2, srti, wA, wB, OffA, OffB, SA, PB);
    k_target<<<N / 4, 256, 0, stream>>>(sdst, srtv, SA, PB, b1, hA);

    // layer 2
    k_proj<<<N / 16, 256, 0, stream>>>(hA, W2, as2, ad2, h2, ssrc, sdst);
    k_rank<<<H * 16, 256, 0, stream>>>(ssrc, srtv, srti);
    k_s1<<<H * 64, 128, 0, stream>>>(h2, srti, srtv, wA, wB, TA, TB);
    k_s2<<<H, 128, 0, stream>>>(TA, TB, OffA, OffB, SA, PB);
    k_s3<<<H * 64, 128, 0, stream>>>(h2, srti, wA, wB, OffA, OffB, SA, PB);
    k_target<<<N / 4, 256, 0, stream>>>(sdst, srtv, SA, PB, b2, hB);

    k_heads<<<N / 4, 256, 0, stream>>>(hB, W_act, b_act, W_cri, b_cri, out);
}

// Round 2
// 129.658 us; speedup vs baseline: 2.6115x; 2.6115x over previous
//
#include <hip/hip_runtime.h>
#include <hip/hip_bf16.h>

// GAT on fully-connected graph, N=4096, F=D=64, H=4, OUT=2.
// e[t,s,h]=lrelu(dst_t+src_s); exp(lrelu) factors per branch:
//   src > -dst : weight = e^{dst} * e^{src}
//   src <= -dst: weight = e^{0.2 dst} * e^{0.2 src}
// Sort sources per head; suffix sums (pos branch) + prefix sums (neg branch)
// of weight*h2 over sorted order; each target = rank(-dst) + two 65-float rows.

#define N 4096
#define D 64
#define H 4
#define HD 256
#define TS 66           // row stride of SA/PB tables (65 cols: 64 dims + weight)
#define RCHUNK 16       // j-chunks for rank computation
#define RJ (N / RCHUNK) // 256

// ---------------- encoder: h0 = relu(x @ W_enc + b_enc) ----------------
__global__ __launch_bounds__(256) void k_encoder(const float* __restrict__ x,
                                                 const float* __restrict__ W,
                                                 const float* __restrict__ b,
                                                 float* __restrict__ h0) {
    __shared__ float Ws[64 * 64];
    __shared__ float xs[4][64];
    int tid = threadIdx.x;
    for (int i = tid; i < 1024; i += 256) ((float4*)Ws)[i] = ((const float4*)W)[i];
    int lr = tid >> 6, lane = tid & 63;
    int row = blockIdx.x * 4 + lr;
    xs[lr][lane] = x[row * 64 + lane];
    __syncthreads();
    float acc = b[lane];
#pragma unroll
    for (int k = 0; k < 64; ++k) acc = fmaf(xs[lr][k], Ws[k * 64 + lane], acc);
    h0[row * 64 + lane] = fmaxf(acc, 0.f);
}

// ---------------- proj: h2 = hin @ W ; ssrc/sdst = einsum(h2, a) ----------------
__global__ __launch_bounds__(256) void k_proj(const float* __restrict__ hin,
                                              const float* __restrict__ W,
                                              const float* __restrict__ asrc,
                                              const float* __restrict__ adst,
                                              float* __restrict__ h2,
                                              float* __restrict__ ssrc,   // [H][N]
                                              float* __restrict__ sdst) { // [H][N]
    __shared__ float Ws[64 * 256];  // 64 KB
    int tid = threadIdx.x;
    for (int i = tid; i < 4096; i += 256) ((float4*)Ws)[i] = ((const float4*)W)[i];
    int lane = tid & 63, w = tid >> 6;
    float4 av = ((const float4*)asrc)[lane];
    float4 bv = ((const float4*)adst)[lane];
    __syncthreads();
    int r0 = blockIdx.x * 16;
    for (int rr = 0; rr < 4; ++rr) {
        int row = r0 + w * 4 + rr;
        float hval = hin[row * 64 + lane];
        float a0 = 0.f, a1 = 0.f, a2 = 0.f, a3 = 0.f;
#pragma unroll
        for (int k = 0; k < 64; ++k) {
            float hk = __shfl(hval, k);
            float4 wv = ((const float4*)(Ws + k * 256))[lane];
            a0 = fmaf(hk, wv.x, a0);
            a1 = fmaf(hk, wv.y, a1);
            a2 = fmaf(hk, wv.z, a2);
            a3 = fmaf(hk, wv.w, a3);
        }
        ((float4*)(h2 + row * 256))[lane] = make_float4(a0, a1, a2, a3);
        float ps = a0 * av.x + a1 * av.y + a2 * av.z + a3 * av.w;
        float pd = a0 * bv.x + a1 * bv.y + a2 * bv.z + a3 * bv.w;
#pragma unroll
        for (int off = 8; off > 0; off >>= 1) {
            ps += __shfl_down(ps, off);
            pd += __shfl_down(pd, off);
        }
        if ((lane & 15) == 0) {
            int h = lane >> 4;
            ssrc[h * N + row] = ps;
            sdst[h * N + row] = pd;
        }
    }
}

// ---------------- rank, stage 1: partial counts over j-chunks ----------------
// grid (H*16, RCHUNK); block 256. Deterministic, no atomics.
__global__ __launch_bounds__(256) void k_rank_part(const float* __restrict__ ssrc,
                                                   int* __restrict__ partial) { // [RCHUNK][H][N]
    __shared__ __align__(16) float vs[RJ];
    int h = blockIdx.x >> 4, bi = blockIdx.x & 15;
    int c = blockIdx.y;
    int tid = threadIdx.x;
    vs[tid] = ssrc[h * N + c * RJ + tid];
    __syncthreads();
    int i = bi * 256 + tid;
    float vi = ssrc[h * N + i];
    int jbase = c * RJ;
    int rank = 0;
    const float4* vs4 = (const float4*)vs;
#pragma unroll 4
    for (int j4 = 0; j4 < RJ / 4; ++j4) {
        float4 q = vs4[j4];
        int jb = jbase + (j4 << 2);
        rank += (q.x < vi || (q.x == vi && jb < i));
        rank += (q.y < vi || (q.y == vi && jb + 1 < i));
        rank += (q.z < vi || (q.z == vi && jb + 2 < i));
        rank += (q.w < vi || (q.w == vi && jb + 3 < i));
    }
    partial[(c * H + h) * N + i] = rank;
}

// ---------------- rank, stage 2: reduce partials + scatter ----------------
__global__ __launch_bounds__(256) void k_rank_reduce(const float* __restrict__ ssrc,
                                                     const int* __restrict__ partial,
                                                     float* __restrict__ srtv,
                                                     int* __restrict__ srti) {
    int h = blockIdx.x >> 4, bi = blockIdx.x & 15;
    int i = bi * 256 + threadIdx.x;
    int rank = 0;
#pragma unroll
    for (int c = 0; c < RCHUNK; ++c) rank += partial[(c * H + h) * N + i];
    srtv[h * N + rank] = ssrc[h * N + i];
    srti[h * N + rank] = i;
}

// ---------------- S1: per-chunk totals + weight arrays ----------------
__global__ __launch_bounds__(128) void k_s1(const float* __restrict__ h2,
                                            const int* __restrict__ srti,
                                            const float* __restrict__ srtv,
                                            float* __restrict__ wA, float* __restrict__ wB,
                                            float* __restrict__ TA, float* __restrict__ TB) {
    int h = blockIdx.x >> 6, c = blockIdx.x & 63, col = threadIdx.x;
    __shared__ int pj[64];
    __shared__ float wa[64], wb[64];
    int j0 = c * 64;
    float m1 = srtv[h * N + N - 1];
    if (col < 64) {
        int j = j0 + col;
        pj[col] = srti[h * N + j];
        float sv = srtv[h * N + j];
        float a = expf(sv - m1);
        float b = expf(0.2f * (sv - m1));
        wa[col] = a; wb[col] = b;
        wA[h * N + j] = a; wB[h * N + j] = b;
    }
    __syncthreads();
    if (col >= 65) return;
    float accA = 0.f, accB = 0.f;
#pragma unroll 8
    for (int j = 0; j < 64; ++j) {
        float val = (col < 64) ? h2[pj[j] * HD + h * 64 + col] : 1.0f;
        accA = fmaf(wa[j], val, accA);
        accB = fmaf(wb[j], val, accB);
    }
    TA[(h * 64 + c) * TS + col] = accA;
    TB[(h * 64 + c) * TS + col] = accB;
}

// ---------------- S2: scan chunk totals -> offsets; boundary rows ----------------
__global__ __launch_bounds__(128) void k_s2(const float* __restrict__ TA,
                                            const float* __restrict__ TB,
                                            float* __restrict__ OffA, float* __restrict__ OffB,
                                            float* __restrict__ SA, float* __restrict__ PB) {
    int h = blockIdx.x, col = threadIdx.x;
    if (col >= 65) return;
    float acc = 0.f;
#pragma unroll 8
    for (int c = 63; c >= 0; --c) {  // suffix offsets for A
        OffA[(h * 64 + c) * TS + col] = acc;
        acc += TA[(h * 64 + c) * TS + col];
    }
    acc = 0.f;
#pragma unroll 8
    for (int c = 0; c < 64; ++c) {   // prefix offsets for B
        OffB[(h * 64 + c) * TS + col] = acc;
        acc += TB[(h * 64 + c) * TS + col];
    }
    SA[(size_t)(h * (N + 1) + N) * TS + col] = 0.f;  // SA[N] = 0
    PB[(size_t)(h * (N + 1) + 0) * TS + col] = 0.f;  // PB[0] = 0
}

// ---------------- S3: full suffix/prefix tables ----------------
__global__ __launch_bounds__(128) void k_s3(const float* __restrict__ h2,
                                            const int* __restrict__ srti,
                                            const float* __restrict__ wA, const float* __restrict__ wB,
                                            const float* __restrict__ OffA, const float* __restrict__ OffB,
                                            float* __restrict__ SA, float* __restrict__ PB) {
    int h = blockIdx.x >> 6, c = blockIdx.x & 63, col = threadIdx.x;
    __shared__ int pj[64];
    __shared__ float wa[64], wb[64];
    int j0 = c * 64;
    if (col < 64) {
        pj[col] = srti[h * N + j0 + col];
        wa[col] = wA[h * N + j0 + col];
        wb[col] = wB[h * N + j0 + col];
    }
    __syncthreads();
    if (col >= 65) return;
    float v[64];
#pragma unroll
    for (int j = 0; j < 64; ++j)
        v[j] = (col < 64) ? h2[pj[j] * HD + h * 64 + col] : 1.0f;
    float acc = OffA[(h * 64 + c) * TS + col];
#pragma unroll
    for (int j = 63; j >= 0; --j) {  // SA[i] = sum_{j>=i} wA_j * v_j
        acc = fmaf(wa[j], v[j], acc);
        SA[(size_t)(h * (N + 1) + j0 + j) * TS + col] = acc;
    }
    acc = OffB[(h * 64 + c) * TS + col];
#pragma unroll
    for (int j = 0; j < 64; ++j) {   // PB[i] = sum_{j<i} wB_j * v_j
        acc = fmaf(wb[j], v[j], acc);
        PB[(size_t)(h * (N + 1) + j0 + j + 1) * TS + col] = acc;
    }
}

// ---------------- target: blend tables per (t,h), mean heads, +bias, relu ----------------
__global__ __launch_bounds__(256) void k_target(const float* __restrict__ sdst, // [H][N]
                                                const float* __restrict__ srtv, // [H][N]
                                                const float* __restrict__ SA,
                                                const float* __restrict__ PB,
                                                const float* __restrict__ bias,
                                                float* __restrict__ hout) {
    int t = blockIdx.x * 4 + (threadIdx.x >> 6);
    int lane = threadIdx.x & 63;
    float acc = 0.f;
#pragma unroll
    for (int h = 0; h < H; ++h) {
        const float* sv = srtv + h * N;
        float dst = sdst[h * N + t];
        float thr = -dst;
        float m1 = sv[N - 1];
        // two-level ballot search: k = #{j : sv[j] <= thr}
        unsigned long long b1 = __ballot(sv[lane * 64] <= thr);
        int c1 = __popcll(b1);
        int seg = c1 > 0 ? c1 - 1 : 0;
        unsigned long long b2 = __ballot(sv[seg * 64 + lane] <= thr);
        int k = seg * 64 + __popcll(b2);
        float u = dst + m1;
        float g = fmaxf(u, 0.2f * u);          // keeps both exps <= 1
        float wAt = expf(u - g);
        float wBt = expf(0.2f * u - g);
        const float* sa = SA + (size_t)(h * (N + 1) + k) * TS;
        const float* pb = PB + (size_t)(h * (N + 1) + k) * TS;
        float num = wAt * sa[lane] + wBt * pb[lane];
        float den = wAt * sa[64] + wBt * pb[64];
        acc += num / den;
    }
    acc = acc * 0.25f + bias[lane];
    hout[t * 64 + lane] = fmaxf(acc, 0.f);
}

// ---------------- heads: logits (clip, abs col1) + values ----------------
__global__ __launch_bounds__(256) void k_heads(const float* __restrict__ h,
                                               const float* __restrict__ Wact,
                                               const float* __restrict__ bact,
                                               const float* __restrict__ Wcri,
                                               const float* __restrict__ bcri,
                                               float* __restrict__ out) {
    int t = blockIdx.x * 4 + (threadIdx.x >> 6);
    int lane = threadIdx.x & 63;
    float hv = h[t * 64 + lane];
    float p0 = hv * Wact[lane * 2 + 0];
    float p1 = hv * Wact[lane * 2 + 1];
    float p2 = hv * Wcri[lane];
#pragma unroll
    for (int off = 32; off > 0; off >>= 1) {
        p0 += __shfl_down(p0, off);
        p1 += __shfl_down(p1, off);
        p2 += __shfl_down(p2, off);
    }
    if (lane == 0) {
        float l0 = fminf(fmaxf(p0 + bact[0], -5.f), 5.f);
        float l1 = fminf(fmaxf(p1 + bact[1], -5.f), 5.f);
        out[t * 2 + 0] = l0;
        out[t * 2 + 1] = fabsf(l1);
        out[2 * N + t] = p2 + bcri[0];
    }
}

extern "C" void kernel_launch(void* const* d_in, const int* in_sizes, int n_in,
                              void* d_out, int out_size, void* d_ws, size_t ws_size,
                              hipStream_t stream) {
    (void)in_sizes; (void)n_in; (void)out_size; (void)ws_size;
    const float* x     = (const float*)d_in[0];
    const float* W_enc = (const float*)d_in[1];
    const float* b_enc = (const float*)d_in[2];
    const float* W1    = (const float*)d_in[3];
    const float* as1   = (const float*)d_in[4];
    const float* ad1   = (const float*)d_in[5];
    const float* b1    = (const float*)d_in[6];
    const float* W2    = (const float*)d_in[7];
    const float* as2   = (const float*)d_in[8];
    const float* ad2   = (const float*)d_in[9];
    const float* b2    = (const float*)d_in[10];
    const float* W_act = (const float*)d_in[11];
    const float* b_act = (const float*)d_in[12];
    const float* W_cri = (const float*)d_in[13];
    const float* b_cri = (const float*)d_in[14];
    float* out = (float*)d_out;

    float* p = (float*)d_ws;
    float* h0   = p; p += N * D;
    float* hA   = p; p += N * D;
    float* hB   = p; p += N * D;
    float* h2   = p; p += N * HD;
    float* ssrc = p; p += H * N;
    float* sdst = p; p += H * N;
    float* srtv = p; p += H * N;
    int*   srti = (int*)p; p += H * N;
    float* wA   = p; p += H * N;
    float* wB   = p; p += H * N;
    float* TA   = p; p += H * 64 * TS;
    float* TB   = p; p += H * 64 * TS;
    float* OffA = p; p += H * 64 * TS;
    float* OffB = p; p += H * 64 * TS;
    float* SA   = p; p += (size_t)H * (N + 1) * TS;
    float* PB   = p; p += (size_t)H * (N + 1) * TS;
    int*   rpart = (int*)p; p += RCHUNK * H * N;

    dim3 rp_grid(H * 16, RCHUNK);

    k_encoder<<<N / 4, 256, 0, stream>>>(x, W_enc, b_enc, h0);

    // layer 1
    k_proj<<<N / 16, 256, 0, stream>>>(h0, W1, as1, ad1, h2, ssrc, sdst);
    k_rank_part<<<rp_grid, 256, 0, stream>>>(ssrc, rpart);
    k_rank_reduce<<<H * 16, 256, 0, stream>>>(ssrc, rpart, srtv, srti);
    k_s1<<<H * 64, 128, 0, stream>>>(h2, srti, srtv, wA, wB, TA, TB);
    k_s2<<<H, 128, 0, stream>>>(TA, TB, OffA, OffB, SA, PB);
    k_s3<<<H * 64, 128, 0, stream>>>(h2, srti, wA, wB, OffA, OffB, SA, PB);
    k_target<<<N / 4, 256, 0, stream>>>(sdst, srtv, SA, PB, b1, hA);

    // layer 2
    k_proj<<<N / 16, 256, 0, stream>>>(hA, W2, as2, ad2, h2, ssrc, sdst);
    k_rank_part<<<rp_grid, 256, 0, stream>>>(ssrc, rpart);
    k_rank_reduce<<<H * 16, 256, 0, stream>>>(ssrc, rpart, srtv, srti);
    k_s1<<<H * 64, 128, 0, stream>>>(h2, srti, srtv, wA, wB, TA, TB);
    k_s2<<<H, 128, 0, stream>>>(TA, TB, OffA, OffB, SA, PB);
    k_s3<<<H * 64, 128, 0, stream>>>(h2, srti, wA, wB, OffA, OffB, SA, PB);
    k_target<<<N / 4, 256, 0, stream>>>(sdst, srtv, SA, PB, b2, hB);

    k_heads<<<N / 4, 256, 0, stream>>>(hB, W_act, b_act, W_cri, b_cri, out);
}